// Round 15
// baseline (1369.599 us; speedup 1.0000x reference)
//
#include <hip/hip_runtime.h>

// Qwen2.5-VL vision tower forward, MI355X gfx950 — round 14.
// Changes vs r13: (1) cvt kernels process 4 chunks/thread (coalesced, fewer
// blocks) to push streaming BW toward the 6.3 TB/s ceiling; (2) if ws_size
// is large enough, m1/m2 weight conversion folds into the single pre-loop
// cvtall (no post-loop cvtmm); fallback path preserved. All compute kernels
// byte-identical to r13 (= r7-proven GEMM/attn configs).

typedef __bf16 bf16x8 __attribute__((ext_vector_type(8)));
typedef float  f32x4  __attribute__((ext_vector_type(4)));
typedef unsigned short u16;

#define DEV __device__ __forceinline__

DEV u16 f2bf(float f) {                       // RNE f32 -> bf16 bits
    union { float f; unsigned u; } v; v.f = f;
    unsigned r = v.u + 0x7FFFu + ((v.u >> 16) & 1u);
    return (u16)(r >> 16);
}
DEV float bf2f(u16 b) {
    union { float f; unsigned u; } v; v.u = ((unsigned)b) << 16; return v.f;
}

DEV void gload16(const u16* g, u16* l) {      // async global->LDS, 16B/lane
    __builtin_amdgcn_global_load_lds(
        (const __attribute__((address_space(1))) unsigned int*)g,
        (__attribute__((address_space(3))) unsigned int*)l, 16, 0, 0);
}

enum { EPI_NONE = 0, EPI_BIAS = 1, EPI_BIAS_RESID = 2, EPI_BIAS_GELU = 3, EPI_PART = 4 };

DEV unsigned xcd_map(unsigned lin, unsigned nwg) {
    unsigned q = nwg >> 3, r = nwg & 7, xc = lin & 7, off = lin >> 3;
    return (xc < r ? xc * (q + 1) : r * (q + 1) + (xc - r) * q) + off;
}

// One 8-element chunk of an f32->bf16 padded conversion.
DEV void cvt_chunk(const float* __restrict__ s, u16* __restrict__ d,
                   int idx, int Rs, int Cs, int Cp)
{
    int cpc = Cp >> 3;
    int row = idx / cpc;
    int c0  = (idx - row * cpc) * 8;
    u16 v[8];
    if (row < Rs && c0 + 8 <= Cs) {
        float4 a = *reinterpret_cast<const float4*>(&s[(size_t)row * Cs + c0]);
        float4 b = *reinterpret_cast<const float4*>(&s[(size_t)row * Cs + c0 + 4]);
        v[0] = f2bf(a.x); v[1] = f2bf(a.y); v[2] = f2bf(a.z); v[3] = f2bf(a.w);
        v[4] = f2bf(b.x); v[5] = f2bf(b.y); v[6] = f2bf(b.z); v[7] = f2bf(b.w);
    } else {
#pragma unroll
        for (int j = 0; j < 8; ++j) {
            int c = c0 + j;
            v[j] = (row < Rs && c < Cs) ? f2bf(s[(size_t)row * Cs + c]) : (u16)0;
        }
    }
    *reinterpret_cast<uint4*>(&d[(size_t)row * Cp + c0]) =
        *reinterpret_cast<const uint4*>(v);
}

// Segment dispatch for one chunk index (0 .. C8).
DEV void cvt_dispatch(int idx,
                      const float* pixel, const float* patchw, const float* qkvw,
                      const float* projw, const float* gatew, const float* upw,
                      const float* downw, const float* m1w, const float* m2w,
                      u16* pix16, u16* pw16, u16* qkvw16, u16* projw16,
                      u16* guw16, u16* downw16, u16* m1w16, u16* m2w16)
{
    const int C0 = 252928, C1 = 447488, C2 = 2905088, C3 = 3724288;
    const int C4 = 5936128, C5 = 8147968, C6 = 10359808;
    const int C7 = 13636608, C8 = 15930368;
    if (idx < C0) {
        cvt_chunk(pixel, pix16, idx, 1600, 1176, 1216);
    } else if (idx < C1) {
        cvt_chunk(patchw, pw16, idx - C0, 1280, 1176, 1216);
    } else if (idx < C2) {
        cvt_chunk(qkvw, qkvw16, idx - C1, 15360, 1280, 1280);
    } else if (idx < C3) {
        cvt_chunk(projw, projw16, idx - C2, 5120, 1280, 1280);
    } else if (idx < C4) {
        int loc = idx - C3; int l = loc / 552960; int wi = loc - l * 552960;
        cvt_chunk(gatew + (size_t)l * 4377600, guw16 + (size_t)l * 8847360,
                  wi, 3420, 1280, 1280);
    } else if (idx < C5) {
        int loc = idx - C4; int l = loc / 552960; int wi = loc - l * 552960;
        cvt_chunk(upw + (size_t)l * 4377600, guw16 + (size_t)l * 8847360 + 4423680,
                  wi, 3420, 1280, 1280);
    } else if (idx < C6) {
        int loc = idx - C5; int l = loc / 552960; int wi = loc - l * 552960;
        cvt_chunk(downw + (size_t)l * 4377600, downw16 + (size_t)l * 4423680,
                  wi, 1280, 3420, 3456);
    } else if (idx < C7) {
        cvt_chunk(m1w, m1w16, idx - C6, 5120, 5120, 5120);
    } else if (idx < C8) {
        cvt_chunk(m2w, m2w16, idx - C7, 3584, 5120, 5120);
    }
}

// 4 chunks/thread, block covers 1024 consecutive chunks. total = chunk count.
__global__ void cvtall_kernel(const float* __restrict__ pixel, const float* __restrict__ patchw,
                              const float* __restrict__ qkvw,  const float* __restrict__ projw,
                              const float* __restrict__ gatew, const float* __restrict__ upw,
                              const float* __restrict__ downw, const float* __restrict__ m1w,
                              const float* __restrict__ m2w,
                              u16* pix16, u16* pw16, u16* qkvw16, u16* projw16,
                              u16* guw16, u16* downw16, u16* m1w16, u16* m2w16,
                              int total)
{
    int base = blockIdx.x * 1024 + threadIdx.x;
#pragma unroll
    for (int j = 0; j < 4; ++j) {
        int idx = base + j * 256;
        if (idx < total)
            cvt_dispatch(idx, pixel, patchw, qkvw, projw, gatew, upw, downw, m1w, m2w,
                         pix16, pw16, qkvw16, projw16, guw16, downw16, m1w16, m2w16);
    }
}

// Post-loop m1/m2 conversion (small-ws fallback), 4 chunks/thread.
__global__ void cvtmm_kernel(const float* __restrict__ m1w, const float* __restrict__ m2w,
                             u16* m1w16, u16* m2w16)
{
    int base = blockIdx.x * 1024 + threadIdx.x;
    const int N7 = 3276800, NT = 5570560;
#pragma unroll
    for (int j = 0; j < 4; ++j) {
        int idx = base + j * 256;
        if (idx < NT) {
            if (idx < N7) cvt_chunk(m1w, m1w16, idx, 5120, 5120, 5120);
            else          cvt_chunk(m2w, m2w16, idx - N7, 3584, 5120, 5120);
        }
    }
}

// Combined gate|up padded bias: [4][6912] f32.
__global__ void gub_kernel(const float* __restrict__ gb, const float* __restrict__ ub,
                           float* __restrict__ dst)
{
    int i = blockIdx.x * 256 + threadIdx.x;
    if (i >= 4 * 6912) return;
    int l = i / 6912, c = i - l * 6912;
    float v = 0.f;
    if (c < 3456) { if (c < 3420) v = gb[l * 3420 + c]; }
    else { int c2 = c - 3456; if (c2 < 3420) v = ub[l * 3420 + c2]; }
    dst[i] = v;
}

// out(RxC) = A(RxKp) @ B(CxKp)^T, bf16 in. 128x128 tile, BK=32, ring-3 LDS,
// counted vmcnt, chunk-XOR swizzle. Split-K via blockIdx.z (EPI_PART).
template <int EPI, bool OF32>
__global__ __launch_bounds__(256, 3)
void gemm16_kernel(const u16* __restrict__ A, const u16* __restrict__ B,
                   const float* __restrict__ bias, const float* __restrict__ resid,
                   void* __restrict__ outp, int Kp, int ldc, int Rlim,
                   int ktn, size_t zstride)
{
    __shared__ u16 sA[3][4096];
    __shared__ u16 sB[3][4096];
    const int tid  = threadIdx.x;
    const int lane = tid & 63;
    const int w    = tid >> 6;

    const unsigned gy  = gridDim.y;
    const unsigned nwg = gridDim.x * gy;
    const unsigned lin = blockIdx.x + blockIdx.y * gridDim.x;
    const unsigned id2 = xcd_map(lin, nwg);
    const int c0 = (int)(id2 / gy) * 128;
    const int r0 = (int)(id2 - (id2 / gy) * gy) * 128;

    const int wr  = (w >> 1) * 64;
    const int wc  = (w & 1) * 64;
    const int l15 = lane & 15;
    const int kk  = (lane >> 4) * 8;
    const int pco = (((lane >> 4) ^ ((l15 >> 1) & 3)) * 8) - kk;

    const int ca  = w * 128 + lane;
    const int cb  = ca + 64;
    const int sza = ((ca & 3) ^ ((ca >> 3) & 3)) * 8;
    const int szb = ((cb & 3) ^ ((cb >> 3) & 3)) * 8;
    const size_t arow0 = (size_t)(r0 + (ca >> 2)) * Kp + sza;
    const size_t brow0 = (size_t)(c0 + (ca >> 2)) * Kp + sza;
    const size_t arow1 = (size_t)(r0 + (cb >> 2)) * Kp + szb;
    const size_t brow1 = (size_t)(c0 + (cb >> 2)) * Kp + szb;

    f32x4 acc[4][4];
#pragma unroll
    for (int i = 0; i < 4; ++i)
#pragma unroll
        for (int j = 0; j < 4; ++j) acc[i][j] = (f32x4){0.f, 0.f, 0.f, 0.f};

    const int kt0 = blockIdx.z * ktn;
    auto stage = [&](int kt, int buf) {
        int k0 = kt * 32;
        gload16(A + arow0 + k0, &sA[buf][ca * 8]);
        gload16(B + brow0 + k0, &sB[buf][ca * 8]);
        gload16(A + arow1 + k0, &sA[buf][cb * 8]);
        gload16(B + brow1 + k0, &sB[buf][cb * 8]);
    };
    auto compute = [&](int buf) {
        bf16x8 af[4], bfr[4];
#pragma unroll
        for (int f = 0; f < 4; ++f) {
            af[f]  = *reinterpret_cast<const bf16x8*>(&sA[buf][(wr + f * 16 + l15) * 32 + kk + pco]);
            bfr[f] = *reinterpret_cast<const bf16x8*>(&sB[buf][(wc + f * 16 + l15) * 32 + kk + pco]);
        }
#pragma unroll
        for (int fr = 0; fr < 4; ++fr)
#pragma unroll
            for (int fc = 0; fc < 4; ++fc)
                acc[fr][fc] = __builtin_amdgcn_mfma_f32_16x16x32_bf16(af[fr], bfr[fc], acc[fr][fc], 0, 0, 0);
    };

    const int NT = ktn;
    stage(kt0, 0);
    if (NT > 1) stage(kt0 + 1, 1);
    int bcur = 0;
    for (int t = 0; t < NT - 1; ++t) {
        asm volatile("s_waitcnt vmcnt(4)" ::: "memory");
        __builtin_amdgcn_s_barrier();
        __builtin_amdgcn_sched_barrier(0);
        if (t + 2 < NT) {
            int bn = bcur + 2; if (bn >= 3) bn -= 3;
            stage(kt0 + t + 2, bn);
        }
        __builtin_amdgcn_sched_barrier(0);
        compute(bcur);
        bcur = (bcur == 2) ? 0 : bcur + 1;
    }
    asm volatile("s_waitcnt vmcnt(0)" ::: "memory");
    __builtin_amdgcn_s_barrier();
    __builtin_amdgcn_sched_barrier(0);
    compute(bcur);

    const int rowb = r0 + wr + (lane >> 4) * 4;
    const int colb = c0 + wc + l15;
    if (EPI == EPI_PART) {
        float* pp = (float*)outp + (size_t)blockIdx.z * zstride;
#pragma unroll
        for (int fc = 0; fc < 4; ++fc) {
            int col = colb + fc * 16;
#pragma unroll
            for (int fr = 0; fr < 4; ++fr)
#pragma unroll
                for (int r2 = 0; r2 < 4; ++r2)
                    pp[(size_t)(rowb + fr * 16 + r2) * ldc + col] = acc[fr][fc][r2];
        }
        return;
    }
#pragma unroll
    for (int fc = 0; fc < 4; ++fc) {
        int col = colb + fc * 16;
        float bv = (EPI != EPI_NONE) ? bias[col] : 0.f;
#pragma unroll
        for (int fr = 0; fr < 4; ++fr) {
#pragma unroll
            for (int r2 = 0; r2 < 4; ++r2) {
                int row = rowb + fr * 16 + r2;
                if (row >= Rlim) continue;
                float v = acc[fr][fc][r2] + bv;
                if (EPI == EPI_BIAS_RESID) v += resid[(size_t)row * ldc + col];
                if (EPI == EPI_BIAS_GELU)  v = 0.5f * v * (1.f + erff(v * 0.70710678118f));
                if (OF32) ((float*)outp)[(size_t)row * ldc + col] = v;
                else      ((u16*)outp)[(size_t)row * ldc + col] = f2bf(v);
            }
        }
    }
}

// 64x128-tile GEMM: 4 blocks/CU. Staging: 2 B chunks + 1 A chunk per thread.
template <int EPI, bool OF32>
__global__ __launch_bounds__(256, 4)
void gemm64_kernel(const u16* __restrict__ A, const u16* __restrict__ B,
                   const float* __restrict__ bias, const float* __restrict__ resid,
                   void* __restrict__ outp, int Kp, int ldc, int Rlim)
{
    __shared__ u16 sA[3][2048];
    __shared__ u16 sB[3][4096];
    const int tid  = threadIdx.x;
    const int lane = tid & 63;
    const int w    = tid >> 6;

    const unsigned gy  = gridDim.y;
    const unsigned nwg = gridDim.x * gy;
    const unsigned lin = blockIdx.x + blockIdx.y * gridDim.x;
    const unsigned id2 = xcd_map(lin, nwg);
    const int c0 = (int)(id2 / gy) * 128;
    const int r0 = (int)(id2 - (id2 / gy) * gy) * 64;

    const int wr  = (w >> 1) * 32;
    const int wc  = (w & 1) * 64;
    const int l15 = lane & 15;
    const int kk  = (lane >> 4) * 8;
    const int pco = (((lane >> 4) ^ ((l15 >> 1) & 3)) * 8) - kk;

    const int cB0 = tid, cB1 = tid + 256, cA = tid;
    const size_t bsrc0 = (size_t)(c0 + (cB0 >> 2)) * Kp + ((cB0 & 3) ^ ((cB0 >> 3) & 3)) * 8;
    const size_t bsrc1 = (size_t)(c0 + (cB1 >> 2)) * Kp + ((cB1 & 3) ^ ((cB1 >> 3) & 3)) * 8;
    const size_t asrc  = (size_t)(r0 + (cA  >> 2)) * Kp + ((cA  & 3) ^ ((cA  >> 3) & 3)) * 8;

    f32x4 acc[2][4];
#pragma unroll
    for (int i = 0; i < 2; ++i)
#pragma unroll
        for (int j = 0; j < 4; ++j) acc[i][j] = (f32x4){0.f, 0.f, 0.f, 0.f};

    auto stage = [&](int kt, int buf) {
        int k0 = kt * 32;
        gload16(B + bsrc0 + k0, &sB[buf][cB0 * 8]);
        gload16(B + bsrc1 + k0, &sB[buf][cB1 * 8]);
        gload16(A + asrc  + k0, &sA[buf][cA * 8]);
    };
    auto compute = [&](int buf) {
        bf16x8 af[2], bfr[4];
#pragma unroll
        for (int f = 0; f < 2; ++f)
            af[f]  = *reinterpret_cast<const bf16x8*>(&sA[buf][(wr + f * 16 + l15) * 32 + kk + pco]);
#pragma unroll
        for (int f = 0; f < 4; ++f)
            bfr[f] = *reinterpret_cast<const bf16x8*>(&sB[buf][(wc + f * 16 + l15) * 32 + kk + pco]);
#pragma unroll
        for (int fr = 0; fr < 2; ++fr)
#pragma unroll
            for (int fc = 0; fc < 4; ++fc)
                acc[fr][fc] = __builtin_amdgcn_mfma_f32_16x16x32_bf16(af[fr], bfr[fc], acc[fr][fc], 0, 0, 0);
    };

    const int NT = Kp >> 5;
    stage(0, 0);
    stage(1, 1);
    int bcur = 0;
    for (int t = 0; t < NT - 1; ++t) {
        asm volatile("s_waitcnt vmcnt(3)" ::: "memory");
        __builtin_amdgcn_s_barrier();
        __builtin_amdgcn_sched_barrier(0);
        if (t + 2 < NT) {
            int bn = bcur + 2; if (bn >= 3) bn -= 3;
            stage(t + 2, bn);
        }
        __builtin_amdgcn_sched_barrier(0);
        compute(bcur);
        bcur = (bcur == 2) ? 0 : bcur + 1;
    }
    asm volatile("s_waitcnt vmcnt(0)" ::: "memory");
    __builtin_amdgcn_s_barrier();
    __builtin_amdgcn_sched_barrier(0);
    compute(bcur);

    const int rowb = r0 + wr + (lane >> 4) * 4;
    const int colb = c0 + wc + l15;
#pragma unroll
    for (int fc = 0; fc < 4; ++fc) {
        int col = colb + fc * 16;
        float bv = (EPI != EPI_NONE) ? bias[col] : 0.f;
#pragma unroll
        for (int fr = 0; fr < 2; ++fr) {
#pragma unroll
            for (int r2 = 0; r2 < 4; ++r2) {
                int row = rowb + fr * 16 + r2;
                if (row >= Rlim) continue;
                float v = acc[fr][fc][r2] + bv;
                if (EPI == EPI_BIAS_RESID) v += resid[(size_t)row * ldc + col];
                if (EPI == EPI_BIAS_GELU)  v = 0.5f * v * (1.f + erff(v * 0.70710678118f));
                if (OF32) ((float*)outp)[(size_t)row * ldc + col] = v;
                else      ((u16*)outp)[(size_t)row * ldc + col] = f2bf(v);
            }
        }
    }
}

// 32x128-tile GEMM for small-B residency-bound shapes (patch, proj, down).
template <int EPI, bool OF32>
__global__ __launch_bounds__(256, 4)
void gemm32_kernel(const u16* __restrict__ A, const u16* __restrict__ B,
                   const float* __restrict__ bias, const float* __restrict__ resid,
                   void* __restrict__ outp, int Kp, int ldc, int Rlim)
{
    __shared__ u16 sA[3][1024];
    __shared__ u16 sB[3][4096];
    const int tid  = threadIdx.x;
    const int lane = tid & 63;
    const int w    = tid >> 6;

    const unsigned gy  = gridDim.y;
    const unsigned nwg = gridDim.x * gy;
    const unsigned lin = blockIdx.x + blockIdx.y * gridDim.x;
    const unsigned id2 = xcd_map(lin, nwg);
    const int c0 = (int)(id2 / gy) * 128;
    const int r0 = (int)(id2 - (id2 / gy) * gy) * 32;

    const int wc  = w * 32;
    const int l15 = lane & 15;
    const int kk  = (lane >> 4) * 8;
    const int pco = (((lane >> 4) ^ ((l15 >> 1) & 3)) * 8) - kk;

    const int cB0 = tid, cB1 = tid + 256, cA = tid & 127;
    const size_t bsrc0 = (size_t)(c0 + (cB0 >> 2)) * Kp + ((cB0 & 3) ^ ((cB0 >> 3) & 3)) * 8;
    const size_t bsrc1 = (size_t)(c0 + (cB1 >> 2)) * Kp + ((cB1 & 3) ^ ((cB1 >> 3) & 3)) * 8;
    const size_t asrc  = (size_t)(r0 + (cA  >> 2)) * Kp + ((cA  & 3) ^ ((cA  >> 3) & 3)) * 8;

    f32x4 acc[2][2];
#pragma unroll
    for (int i = 0; i < 2; ++i)
#pragma unroll
        for (int j = 0; j < 2; ++j) acc[i][j] = (f32x4){0.f, 0.f, 0.f, 0.f};

    auto stage = [&](int kt, int buf) {
        int k0 = kt * 32;
        gload16(B + bsrc0 + k0, &sB[buf][cB0 * 8]);
        gload16(B + bsrc1 + k0, &sB[buf][cB1 * 8]);
        gload16(A + asrc  + k0, &sA[buf][cA * 8]);
    };
    auto compute = [&](int buf) {
        bf16x8 af[2], bfr[2];
#pragma unroll
        for (int f = 0; f < 2; ++f) {
            af[f]  = *reinterpret_cast<const bf16x8*>(&sA[buf][(f * 16 + l15) * 32 + kk + pco]);
            bfr[f] = *reinterpret_cast<const bf16x8*>(&sB[buf][(wc + f * 16 + l15) * 32 + kk + pco]);
        }
#pragma unroll
        for (int fr = 0; fr < 2; ++fr)
#pragma unroll
            for (int fc = 0; fc < 2; ++fc)
                acc[fr][fc] = __builtin_amdgcn_mfma_f32_16x16x32_bf16(af[fr], bfr[fc], acc[fr][fc], 0, 0, 0);
    };

    const int NT = Kp >> 5;
    stage(0, 0);
    stage(1, 1);
    int bcur = 0;
    for (int t = 0; t < NT - 1; ++t) {
        asm volatile("s_waitcnt vmcnt(3)" ::: "memory");
        __builtin_amdgcn_s_barrier();
        __builtin_amdgcn_sched_barrier(0);
        if (t + 2 < NT) {
            int bn = bcur + 2; if (bn >= 3) bn -= 3;
            stage(t + 2, bn);
        }
        __builtin_amdgcn_sched_barrier(0);
        compute(bcur);
        bcur = (bcur == 2) ? 0 : bcur + 1;
    }
    asm volatile("s_waitcnt vmcnt(0)" ::: "memory");
    __builtin_amdgcn_s_barrier();
    __builtin_amdgcn_sched_barrier(0);
    compute(bcur);

    const int rowb = r0 + (lane >> 4) * 4;
    const int colb = c0 + wc + l15;
#pragma unroll
    for (int fc = 0; fc < 2; ++fc) {
        int col = colb + fc * 16;
        float bv = (EPI != EPI_NONE) ? bias[col] : 0.f;
#pragma unroll
        for (int fr = 0; fr < 2; ++fr) {
#pragma unroll
            for (int r2 = 0; r2 < 4; ++r2) {
                int row = rowb + fr * 16 + r2;
                if (row >= Rlim) continue;
                float v = acc[fr][fc][r2] + bv;
                if (EPI == EPI_BIAS_RESID) v += resid[(size_t)row * ldc + col];
                if (EPI == EPI_BIAS_GELU)  v = 0.5f * v * (1.f + erff(v * 0.70710678118f));
                if (OF32) ((float*)outp)[(size_t)row * ldc + col] = v;
                else      ((u16*)outp)[(size_t)row * ldc + col] = f2bf(v);
            }
        }
    }
}

// Split-K reduce: out = [gelu](sum_s part[s] + bias). total4 = R*C/4.
template <int GELU, bool OF32>
__global__ void reduce_kernel(const float* __restrict__ part, const float* __restrict__ bias,
                              void* __restrict__ outp, int C, int S, size_t zstride, int total4)
{
    int i = blockIdx.x * 256 + threadIdx.x;
    if (i >= total4) return;
    int cq = C >> 2;
    int rr = i / cq;
    int cc = (i - rr * cq) * 4;
    size_t bidx = (size_t)rr * C + cc;
    float4 s = *reinterpret_cast<const float4*>(&part[bidx]);
    for (int z = 1; z < S; ++z) {
        float4 p = *reinterpret_cast<const float4*>(&part[z * zstride + bidx]);
        s.x += p.x; s.y += p.y; s.z += p.z; s.w += p.w;
    }
    float4 b = *reinterpret_cast<const float4*>(&bias[cc]);
    s.x += b.x; s.y += b.y; s.z += b.z; s.w += b.w;
    if (GELU) {
        s.x = 0.5f * s.x * (1.f + erff(s.x * 0.70710678118f));
        s.y = 0.5f * s.y * (1.f + erff(s.y * 0.70710678118f));
        s.z = 0.5f * s.z * (1.f + erff(s.z * 0.70710678118f));
        s.w = 0.5f * s.w * (1.f + erff(s.w * 0.70710678118f));
    }
    if (OF32) {
        *reinterpret_cast<float4*>(&((float*)outp)[bidx]) = s;
    } else {
        u16 v[4] = { f2bf(s.x), f2bf(s.y), f2bf(s.z), f2bf(s.w) };
        *reinterpret_cast<uint2*>(&((u16*)outp)[bidx]) = *reinterpret_cast<const uint2*>(v);
    }
}

__global__ void rms_kernel(const float* __restrict__ x, const float* __restrict__ w,
                           u16* __restrict__ out, int cols)
{
    const int row = blockIdx.x;
    const int tid = threadIdx.x;
    const float* xr = x + (size_t)row * cols;
    float ss = 0.f;
    for (int c = tid; c < cols; c += 256) { float v = xr[c]; ss += v * v; }
#pragma unroll
    for (int m = 1; m < 64; m <<= 1) ss += __shfl_xor(ss, m);
    __shared__ float wsum[4];
    if ((tid & 63) == 0) wsum[tid >> 6] = ss;
    __syncthreads();
    float tot = wsum[0] + wsum[1] + wsum[2] + wsum[3];
    float rs = rsqrtf(tot / (float)cols + 1e-6f);
    u16* orow = out + (size_t)row * cols;
    for (int c = tid; c < cols; c += 256) orow[c] = f2bf(xr[c] * rs * w[c]);
}

// In-place RoPE on bf16 q,k halves of qkv.
__global__ void rope_kernel(u16* __restrict__ qkv, const float* __restrict__ cosb,
                            const float* __restrict__ sinb)
{
    int idx = blockIdx.x * 256 + threadIdx.x;   // < 1,024,000
    int n   = idx / 640;
    int rem = idx - n * 640;
    int hh  = rem / 40;
    int d   = rem - hh * 40;
    float c0 = cosb[n * 80 + d];
    float s0 = sinb[n * 80 + d];
    float c1 = cosb[n * 80 + d + 40];
    float s1 = sinb[n * 80 + d + 40];
    size_t base = (size_t)n * 3840 + hh * 80;
    float a = bf2f(qkv[base + d]), b = bf2f(qkv[base + d + 40]);
    qkv[base + d]      = f2bf(a * c0 - b * s0);
    qkv[base + d + 40] = f2bf(b * c1 + a * s1);
    base += 1280;
    a = bf2f(qkv[base + d]); b = bf2f(qkv[base + d + 40]);
    qkv[base + d]      = f2bf(a * c0 - b * s0);
    qkv[base + d + 40] = f2bf(b * c1 + a * s1);
}

// silu(gate)*up from fused [1664][6912] buffer -> packed [1664][3456].
__global__ void silu_mul_kernel(const u16* __restrict__ gu, u16* __restrict__ outb)
{
    int idx = blockIdx.x * 256 + threadIdx.x;
    if (idx >= 1664 * 432) return;
    int row = idx / 432, c8 = (idx - row * 432) * 8;
    u16 gv[8], uv[8];
    *reinterpret_cast<uint4*>(gv) = *reinterpret_cast<const uint4*>(&gu[(size_t)row * 6912 + c8]);
    *reinterpret_cast<uint4*>(uv) = *reinterpret_cast<const uint4*>(&gu[(size_t)row * 6912 + 3456 + c8]);
#pragma unroll
    for (int j = 0; j < 8; ++j) {
        float x = bf2f(gv[j]);
        gv[j] = f2bf(x / (1.f + __expf(-x)) * bf2f(uv[j]));
    }
    *reinterpret_cast<uint4*>(&outb[(size_t)row * 3456 + c8]) = *reinterpret_cast<const uint4*>(gv);
}

// Flash attention (r7-proven): 256 threads, QBLK=64, double-buffered K/V LDS,
// reg-staged loads, conflict-free packed-u32 V transpose, 1 barrier/tile.
__global__ __launch_bounds__(256, 2)
void attn_kernel(const u16* __restrict__ qkv, u16* __restrict__ o)
{
    __shared__ __align__(16) u16      Klds[2][64][104];
    __shared__ __align__(16) unsigned Vt32[2][80][36];
    __shared__ __align__(16) u16      Plds[4][16][72];
    const int tid  = threadIdx.x;
    const int lane = tid & 63;
    const int w    = tid >> 6;
    const int l15  = lane & 15;
    const int kk   = (lane >> 4) * 8;
    unsigned lin = blockIdx.y * 25 + blockIdx.x;
    unsigned id2 = (lin & 7) * 50 + (lin >> 3);
    const int hh = (int)(id2 / 25);
    const int qt = (int)(id2 - hh * 25);
    const float scale = 0.11180339887498949f;

    const int koff = 1280 + hh * 80;
    const int voff = 2560 + hh * 80;

    {
        int r  = tid >> 2;
        int cq = 80 + (tid & 3) * 4;
        *reinterpret_cast<uint2*>(&Klds[0][r][cq]) = make_uint2(0u, 0u);
        *reinterpret_cast<uint2*>(&Klds[1][r][cq]) = make_uint2(0u, 0u);
    }

    const int qrow = qt * 64 + w * 16 + l15;
    bf16x8 aq[3];
#pragma unroll
    for (int s = 0; s < 3; ++s) {
        int d = 32 * s + kk;
        union { bf16x8 v; uint4 q; } uu;
        if (d < 80) uu.q = *reinterpret_cast<const uint4*>(&qkv[(size_t)qrow * 3840 + hh * 80 + d]);
        else        uu.q = make_uint4(0u, 0u, 0u, 0u);
        aq[s] = uu.v;
    }

    const int kc0 = tid, kc1 = tid + 256, kc2 = tid + 512;
    const int kr0 = kc0 / 10, k80 = (kc0 - kr0 * 10) * 8;
    const int kr1 = kc1 / 10, k81 = (kc1 - kr1 * 10) * 8;
    const int kr2 = kc2 / 10, k82 = (kc2 - kr2 * 10) * 8;
    const size_t ksrc0 = (size_t)kr0 * 3840 + koff + k80;
    const size_t ksrc1 = (size_t)kr1 * 3840 + koff + k81;
    const size_t ksrc2 = (size_t)kr2 * 3840 + koff + k82;
    const int rpA = tid & 31, gA = tid >> 5;
    const int gB = 8 + (tid >> 5);
    const size_t vsrcA = (size_t)(2 * rpA) * 3840 + voff + gA * 8;
    const size_t vsrcB = (size_t)(2 * rpA) * 3840 + voff + gB * 8;

    uint4 kg0, kg1, kg2, va0, va1, vb0, vb1;
    auto LOADR = [&](int kb) {
        size_t tb = (size_t)kb * 245760;
        kg0 = *reinterpret_cast<const uint4*>(&qkv[tb + ksrc0]);
        kg1 = *reinterpret_cast<const uint4*>(&qkv[tb + ksrc1]);
        if (tid < 128) kg2 = *reinterpret_cast<const uint4*>(&qkv[tb + ksrc2]);
        va0 = *reinterpret_cast<const uint4*>(&qkv[tb + vsrcA]);
        va1 = *reinterpret_cast<const uint4*>(&qkv[tb + vsrcA + 3840]);
        if (tid < 64) {
            vb0 = *reinterpret_cast<const uint4*>(&qkv[tb + vsrcB]);
            vb1 = *reinterpret_cast<const uint4*>(&qkv[tb + vsrcB + 3840]);
        }
    };
    auto STORE = [&](int b) {
        *reinterpret_cast<uint4*>(&Klds[b][kr0][k80]) = kg0;
        *reinterpret_cast<uint4*>(&Klds[b][kr1][k81]) = kg1;
        if (tid < 128) *reinterpret_cast<uint4*>(&Klds[b][kr2][k82]) = kg2;
        union { uint4 q; u16 h[8]; } xa0, xa1;
        xa0.q = va0; xa1.q = va1;
#pragma unroll
        for (int j = 0; j < 8; ++j)
            Vt32[b][gA * 8 + j][rpA] = (unsigned)xa0.h[j] | ((unsigned)xa1.h[j] << 16);
        if (tid < 64) {
            union { uint4 q; u16 h[8]; } xb0, xb1;
            xb0.q = vb0; xb1.q = vb1;
#pragma unroll
            for (int j = 0; j < 8; ++j)
                Vt32[b][gB * 8 + j][rpA] = (unsigned)xb0.h[j] | ((unsigned)xb1.h[j] << 16);
        }
    };

    f32x4 acc_o[5];
#pragma unroll
    for (int fd = 0; fd < 5; ++fd) acc_o[fd] = (f32x4){0.f, 0.f, 0.f, 0.f};
    float m[4], lsum[4];
#pragma unroll
    for (int r2 = 0; r2 < 4; ++r2) { m[r2] = -__builtin_inff(); lsum[r2] = 0.f; }

    LOADR(0);
    STORE(0);
    __syncthreads();
    int cur = 0;

    for (int kb = 0; kb < 25; ++kb) {
        if (kb < 24) LOADR(kb + 1);

        f32x4 sf[4];
#pragma unroll
        for (int fc = 0; fc < 4; ++fc) {
            f32x4 c = (f32x4){0.f, 0.f, 0.f, 0.f};
#pragma unroll
            for (int s = 0; s < 3; ++s)
                c = __builtin_amdgcn_mfma_f32_16x16x32_bf16(
                        aq[s],
                        *reinterpret_cast<const bf16x8*>(&Klds[cur][fc * 16 + l15][32 * s + kk]),
                        c, 0, 0, 0);
            sf[fc] = c * scale;
        }

        float mx[4];
#pragma unroll
        for (int r2 = 0; r2 < 4; ++r2)
            mx[r2] = fmaxf(fmaxf(sf[0][r2], sf[1][r2]), fmaxf(sf[2][r2], sf[3][r2]));
#pragma unroll
        for (int msk = 1; msk <= 8; msk <<= 1)
#pragma unroll
            for (int r2 = 0; r2 < 4; ++r2)
                mx[r2] = fmaxf(mx[r2], __shfl_xor(mx[r2], msk));
        float alpha[4];
#pragma unroll
        for (int r2 = 0; r2 < 4; ++r2) {
            float mn = fmaxf(m[r2], mx[r2]);
            alpha[r2] = __expf(m[r2] - mn);
            m[r2] = mn;
        }
        float psum[4] = {0.f, 0.f, 0.f, 0.f};
#pragma unroll
        for (int fc = 0; fc < 4; ++fc)
#pragma unroll
            for (int r2 = 0; r2 < 4; ++r2) {
                float p = __expf(sf[fc][r2] - m[r2]);
                sf[fc][r2] = p;
                psum[r2] += p;
            }
#pragma unroll
        for (int msk = 1; msk <= 8; msk <<= 1)
#pragma unroll
            for (int r2 = 0; r2 < 4; ++r2) psum[r2] += __shfl_xor(psum[r2], msk);
#pragma unroll
        for (int r2 = 0; r2 < 4; ++r2) lsum[r2] = lsum[r2] * alpha[r2] + psum[r2];
#pragma unroll
        for (int fd = 0; fd < 5; ++fd)
#pragma unroll
            for (int r2 = 0; r2 < 4; ++r2) acc_o[fd][r2] *= alpha[r2];

        const int prow = (lane >> 4) * 4;
#pragma unroll
        for (int fc = 0; fc < 4; ++fc)
#pragma unroll
            for (int r2 = 0; r2 < 4; ++r2)
                Plds[w][prow + r2][fc * 16 + l15] = f2bf(sf[fc][r2]);

        bf16x8 ap[2];
#pragma unroll
        for (int ks = 0; ks < 2; ++ks)
            ap[ks] = *reinterpret_cast<const bf16x8*>(&Plds[w][l15][32 * ks + kk]);
#pragma unroll
        for (int fd = 0; fd < 5; ++fd) {
            const u16* vrow = reinterpret_cast<const u16*>(&Vt32[cur][fd * 16 + l15][0]);
#pragma unroll
            for (int ks = 0; ks < 2; ++ks)
                acc_o[fd] = __builtin_amdgcn_mfma_f32_16x16x32_bf16(
                        ap[ks],
                        *reinterpret_cast<const bf16x8*>(&vrow[32 * ks + kk]),
                        acc_o[fd], 0, 0, 0);
        }

        if (kb < 24) STORE(cur ^ 1);
        __syncthreads();
        cur ^= 1;
    }

    float inv[4];
#pragma unroll
    for (int r2 = 0; r2 < 4; ++r2) inv[r2] = 1.f / lsum[r2];
    const int orow = qt * 64 + w * 16 + (lane >> 4) * 4;
    const int ocol = hh * 80 + l15;
#pragma unroll
    for (int fd = 0; fd < 5; ++fd)
#pragma unroll
        for (int r2 = 0; r2 < 4; ++r2)
            o[(size_t)(orow + r2) * 1280 + ocol + fd * 16] = f2bf(acc_o[fd][r2] * inv[r2]);
}

extern "C" void kernel_launch(void* const* d_in, const int* in_sizes, int n_in,
                              void* d_out, int out_size, void* d_ws, size_t ws_size,
                              hipStream_t stream)
{
    const float* pixel  = (const float*)d_in[0];
    const float* cosb   = (const float*)d_in[1];
    const float* sinb   = (const float*)d_in[2];
    const float* patchw = (const float*)d_in[3];
    const float* n1w    = (const float*)d_in[4];
    const float* qkvw   = (const float*)d_in[5];
    const float* qkvb   = (const float*)d_in[6];
    const float* projw  = (const float*)d_in[7];
    const float* projb  = (const float*)d_in[8];
    const float* n2w    = (const float*)d_in[9];
    const float* gatew  = (const float*)d_in[10];
    const float* gateb  = (const float*)d_in[11];
    const float* upw    = (const float*)d_in[12];
    const float* upb    = (const float*)d_in[13];
    const float* downw  = (const float*)d_in[14];
    const float* downb  = (const float*)d_in[15];
    const float* lnqw   = (const float*)d_in[16];
    const float* m1w    = (const float*)d_in[17];
    const float* m1b    = (const float*)d_in[18];
    const float* m2w    = (const float*)d_in[19];
    const float* m2b    = (const float*)d_in[20];
    float* out = (float*)d_out;

    char* base = (char*)d_ws;
    float* x      = (float*)(base);                       //  1664x1280 f32
    u16*   h      = (u16*)(base + 8519680);               //  1664x1280
    u16*   qbuf   = (u16*)(base + 12779520);              //  1664x3840
    u16*   pix16  = qbuf;                                 //  alias (pre-loop, 1664x1216)
    u16*   gsep   = (u16*)(base + 25559040);              //  1664x3456
    u16*   o      = gsep;                                 //  alias (attn->proj)
    u16*   pw16   = gsep;                                 //  alias (pre-loop, 1280x1216)
    u16*   gu     = (u16*)(base + 37060608);              //  1664x6912
    u16*   t1     = gu;                                   //  alias (post-loop, 512x5120)
    float* guB    = (float*)(base + 60063744);            //  4x6912 f32
    u16*   qkvw16 = (u16*)(base + 60174336);              //  4x3840x1280
    u16*   projw16= (u16*)(base + 99495936);              //  4x1280x1280
    u16*   guw16  = (u16*)(base + 112603136);             //  4x6912x1280
    u16*   downw16= (u16*)(base + 183382016);             //  4x1280x3456 (end 218.8MB)
    float* part   = (float*)qkvw16;                       //  alias (post-loop, 52.4MB)

    // m1/m2 bf16 placement: fresh space if workspace allows (enables single
    // pre-loop cvt); else alias dead loop regions + post-loop cvtmm.
    const bool bigws = ws_size >= (size_t)307934336;      // 218.8MB + 52.4 + 36.7
    u16* m1w16 = bigws ? (u16*)(base + 218805376)
                       : guw16;                           // alias (post-loop)
    u16* m2w16 = bigws ? (u16*)(base + 218805376 + 52428800)
                       : (u16*)(base + 112603136 + 52428800);

    dim3 blk(256);

    // cvtall: 10,359,808 chunks (pre-loop segs) or 15,930,368 (incl. m1/m2)
    int cvt_total = bigws ? 15930368 : 10359808;
    int cvt_grid  = (cvt_total + 1023) / 1024;
    cvtall_kernel<<<cvt_grid, blk, 0, stream>>>(
        pixel, patchw, qkvw, projw, gatew, upw, downw, m1w, m2w,
        pix16, pw16, qkvw16, projw16, guw16, downw16, m1w16, m2w16, cvt_total);
    gub_kernel<<<108, blk, 0, stream>>>(gateb, upb, guB);

    gemm32_kernel<EPI_NONE, true><<<dim3(10,52), blk, 0, stream>>>(pix16, pw16, nullptr, nullptr, x, 1216, 1280, 1664);
    for (int i = 0; i < 4; ++i) {
        rms_kernel<<<1600, blk, 0, stream>>>(x, n1w + i*1280, h, 1280);
        gemm64_kernel<EPI_BIAS, false><<<dim3(30,26), blk, 0, stream>>>(h, qkvw16 + (size_t)i*4915200, qkvb + i*3840, nullptr, qbuf, 1280, 3840, 1664);
        rope_kernel<<<4000, blk, 0, stream>>>(qbuf, cosb, sinb);
        attn_kernel<<<dim3(25,16), blk, 0, stream>>>(qbuf, o);
        gemm32_kernel<EPI_BIAS_RESID, true><<<dim3(10,52), blk, 0, stream>>>(o, projw16 + (size_t)i*1638400, projb + i*1280, x, x, 1280, 1280, 1664);
        rms_kernel<<<1600, blk, 0, stream>>>(x, n2w + i*1280, h, 1280);
        gemm16_kernel<EPI_BIAS, false><<<dim3(54,13), blk, 0, stream>>>(h, guw16 + (size_t)i*8847360, guB + i*6912, nullptr, gu, 1280, 6912, 1664, 40, 0);
        silu_mul_kernel<<<2808, blk, 0, stream>>>(gu, gsep);
        gemm32_kernel<EPI_BIAS_RESID, true><<<dim3(10,52), blk, 0, stream>>>(gsep, downw16 + (size_t)i*4423680, downb + i*1280, x, x, 3456, 1280, 1664);
    }
    if (!bigws)
        cvtmm_kernel<<<5440, blk, 0, stream>>>(m1w, m2w, m1w16, m2w16);
    rms_kernel<<<1600, blk, 0, stream>>>(x, lnqw, h, 1280);
    gemm16_kernel<EPI_PART, false><<<dim3(40,4,5), blk, 0, stream>>>(h, m1w16, nullptr, nullptr, part, 5120, 5120, 512, 32, 2621440);
    reduce_kernel<1, false><<<2560, blk, 0, stream>>>(part, m1b, t1, 5120, 5, 2621440, 655360);
    gemm16_kernel<EPI_PART, false><<<dim3(28,4,5), blk, 0, stream>>>(t1, m2w16, nullptr, nullptr, part, 5120, 3584, 512, 32, 1835008);
    reduce_kernel<0, true><<<1400, blk, 0, stream>>>(part, m2b, out, 3584, 5, 1835008, 358400);
}

// Round 16
// 1280.244 us; speedup vs baseline: 1.0698x; 1.0698x over previous
//
#include <hip/hip_runtime.h>

// Qwen2.5-VL vision tower forward, MI355X gfx950 — round 15.
// = r13 (best-measured 1297us class) with one fix: cvt kernels restructured
// for memory-level parallelism — resolve 4 chunk addresses, issue all 8
// float4 loads back-to-back, then convert+store. (r14's version serialized
// load->convert->store per chunk, which is why BW didn't move.)

typedef __bf16 bf16x8 __attribute__((ext_vector_type(8)));
typedef float  f32x4  __attribute__((ext_vector_type(4)));
typedef unsigned short u16;

#define DEV __device__ __forceinline__

DEV u16 f2bf(float f) {                       // RNE f32 -> bf16 bits
    union { float f; unsigned u; } v; v.f = f;
    unsigned r = v.u + 0x7FFFu + ((v.u >> 16) & 1u);
    return (u16)(r >> 16);
}
DEV float bf2f(u16 b) {
    union { float f; unsigned u; } v; v.u = ((unsigned)b) << 16; return v.f;
}

DEV void gload16(const u16* g, u16* l) {      // async global->LDS, 16B/lane
    __builtin_amdgcn_global_load_lds(
        (const __attribute__((address_space(1))) unsigned int*)g,
        (__attribute__((address_space(3))) unsigned int*)l, 16, 0, 0);
}

enum { EPI_NONE = 0, EPI_BIAS = 1, EPI_BIAS_RESID = 2, EPI_BIAS_GELU = 3, EPI_PART = 4 };

DEV unsigned xcd_map(unsigned lin, unsigned nwg) {
    unsigned q = nwg >> 3, r = nwg & 7, xc = lin & 7, off = lin >> 3;
    return (xc < r ? xc * (q + 1) : r * (q + 1) + (xc - r) * q) + off;
}

struct CvtIt { const float* sp; u16* dp; int valid; };

// Per-segment item builder; Rs/Cs/Cp are literal at every call site, so the
// divisions lower to magic-multiplies.
DEV CvtIt cvt_mk(const float* s, u16* d, int loc, int Rs, int Cs, int Cp)
{
    int cpc = Cp >> 3;
    int row = loc / cpc;
    int c0  = (loc - row * cpc) * 8;
    CvtIt it;
    it.sp = s + (size_t)row * Cs + c0;
    it.dp = d + (size_t)row * Cp + c0;
    int v = (row < Rs) ? (Cs - c0) : 0;
    it.valid = v >= 8 ? 8 : (v < 0 ? 0 : v);
    return it;
}

DEV CvtIt cvt_resolve(int idx,
                      const float* pixel, const float* patchw, const float* qkvw,
                      const float* projw, const float* gatew, const float* upw,
                      const float* downw,
                      u16* pix16, u16* pw16, u16* qkvw16, u16* projw16,
                      u16* guw16, u16* downw16)
{
    const int C0 = 252928, C1 = 447488, C2 = 2905088, C3 = 3724288;
    const int C4 = 5936128, C5 = 8147968;
    if (idx < C0) return cvt_mk(pixel,  pix16,  idx,      1600, 1176, 1216);
    if (idx < C1) return cvt_mk(patchw, pw16,   idx - C0, 1280, 1176, 1216);
    if (idx < C2) return cvt_mk(qkvw,   qkvw16, idx - C1, 15360, 1280, 1280);
    if (idx < C3) return cvt_mk(projw,  projw16,idx - C2, 5120, 1280, 1280);
    if (idx < C4) {
        int t = idx - C3; int l = t / 552960; int loc = t - l * 552960;
        return cvt_mk(gatew + (size_t)l * 4377600, guw16 + (size_t)l * 8847360,
                      loc, 3420, 1280, 1280);
    }
    if (idx < C5) {
        int t = idx - C4; int l = t / 552960; int loc = t - l * 552960;
        return cvt_mk(upw + (size_t)l * 4377600,
                      guw16 + (size_t)l * 8847360 + 4423680, loc, 3420, 1280, 1280);
    }
    int t = idx - C5; int l = t / 552960; int loc = t - l * 552960;
    return cvt_mk(downw + (size_t)l * 4377600, downw16 + (size_t)l * 4423680,
                  loc, 1280, 3420, 3456);
}

// Pre-loop conversions: 10,359,808 chunks, 4/thread, loads issued up-front.
__global__ void cvtall_kernel(const float* __restrict__ pixel, const float* __restrict__ patchw,
                              const float* __restrict__ qkvw,  const float* __restrict__ projw,
                              const float* __restrict__ gatew, const float* __restrict__ upw,
                              const float* __restrict__ downw,
                              u16* pix16, u16* pw16, u16* qkvw16, u16* projw16,
                              u16* guw16, u16* downw16)
{
    const int total = 10359808;
    int base = blockIdx.x * 1024 + threadIdx.x;
    CvtIt it[4];
#pragma unroll
    for (int j = 0; j < 4; ++j) {
        int idx = base + j * 256;
        if (idx < total)
            it[j] = cvt_resolve(idx, pixel, patchw, qkvw, projw, gatew, upw, downw,
                                pix16, pw16, qkvw16, projw16, guw16, downw16);
        else { it[j].sp = nullptr; it[j].dp = nullptr; it[j].valid = 0; }
    }
    float4 a[4], b[4];
#pragma unroll
    for (int j = 0; j < 4; ++j)
        if (it[j].valid == 8) {
            a[j] = *reinterpret_cast<const float4*>(it[j].sp);
            b[j] = *reinterpret_cast<const float4*>(it[j].sp + 4);
        }
#pragma unroll
    for (int j = 0; j < 4; ++j) {
        if (!it[j].dp) continue;
        u16 v[8];
        if (it[j].valid == 8) {
            v[0]=f2bf(a[j].x); v[1]=f2bf(a[j].y); v[2]=f2bf(a[j].z); v[3]=f2bf(a[j].w);
            v[4]=f2bf(b[j].x); v[5]=f2bf(b[j].y); v[6]=f2bf(b[j].z); v[7]=f2bf(b[j].w);
        } else {
#pragma unroll
            for (int e = 0; e < 8; ++e)
                v[e] = (e < it[j].valid) ? f2bf(it[j].sp[e]) : (u16)0;
        }
        *reinterpret_cast<uint4*>(it[j].dp) = *reinterpret_cast<const uint4*>(v);
    }
}

// Post-loop m1/m2 conversion (dst aliases loop-live regions): 5,570,560 chunks.
__global__ void cvtmm_kernel(const float* __restrict__ m1w, const float* __restrict__ m2w,
                             u16* m1w16, u16* m2w16)
{
    const int N7 = 3276800, NT = 5570560;
    int base = blockIdx.x * 1024 + threadIdx.x;
    CvtIt it[4];
#pragma unroll
    for (int j = 0; j < 4; ++j) {
        int idx = base + j * 256;
        if (idx < NT) {
            if (idx < N7) it[j] = cvt_mk(m1w, m1w16, idx, 5120, 5120, 5120);
            else          it[j] = cvt_mk(m2w, m2w16, idx - N7, 3584, 5120, 5120);
        } else { it[j].sp = nullptr; it[j].dp = nullptr; it[j].valid = 0; }
    }
    float4 a[4], b[4];
#pragma unroll
    for (int j = 0; j < 4; ++j)
        if (it[j].valid == 8) {
            a[j] = *reinterpret_cast<const float4*>(it[j].sp);
            b[j] = *reinterpret_cast<const float4*>(it[j].sp + 4);
        }
#pragma unroll
    for (int j = 0; j < 4; ++j) {
        if (!it[j].dp) continue;
        u16 v[8];
        v[0]=f2bf(a[j].x); v[1]=f2bf(a[j].y); v[2]=f2bf(a[j].z); v[3]=f2bf(a[j].w);
        v[4]=f2bf(b[j].x); v[5]=f2bf(b[j].y); v[6]=f2bf(b[j].z); v[7]=f2bf(b[j].w);
        *reinterpret_cast<uint4*>(it[j].dp) = *reinterpret_cast<const uint4*>(v);
    }
}

// Combined gate|up padded bias: [4][6912] f32.
__global__ void gub_kernel(const float* __restrict__ gb, const float* __restrict__ ub,
                           float* __restrict__ dst)
{
    int i = blockIdx.x * 256 + threadIdx.x;
    if (i >= 4 * 6912) return;
    int l = i / 6912, c = i - l * 6912;
    float v = 0.f;
    if (c < 3456) { if (c < 3420) v = gb[l * 3420 + c]; }
    else { int c2 = c - 3456; if (c2 < 3420) v = ub[l * 3420 + c2]; }
    dst[i] = v;
}

// out(RxC) = A(RxKp) @ B(CxKp)^T, bf16 in. 128x128 tile, BK=32, ring-3 LDS,
// counted vmcnt, chunk-XOR swizzle. Split-K via blockIdx.z (EPI_PART).
template <int EPI, bool OF32>
__global__ __launch_bounds__(256, 3)
void gemm16_kernel(const u16* __restrict__ A, const u16* __restrict__ B,
                   const float* __restrict__ bias, const float* __restrict__ resid,
                   void* __restrict__ outp, int Kp, int ldc, int Rlim,
                   int ktn, size_t zstride)
{
    __shared__ u16 sA[3][4096];
    __shared__ u16 sB[3][4096];
    const int tid  = threadIdx.x;
    const int lane = tid & 63;
    const int w    = tid >> 6;

    const unsigned gy  = gridDim.y;
    const unsigned nwg = gridDim.x * gy;
    const unsigned lin = blockIdx.x + blockIdx.y * gridDim.x;
    const unsigned id2 = xcd_map(lin, nwg);
    const int c0 = (int)(id2 / gy) * 128;
    const int r0 = (int)(id2 - (id2 / gy) * gy) * 128;

    const int wr  = (w >> 1) * 64;
    const int wc  = (w & 1) * 64;
    const int l15 = lane & 15;
    const int kk  = (lane >> 4) * 8;
    const int pco = (((lane >> 4) ^ ((l15 >> 1) & 3)) * 8) - kk;

    const int ca  = w * 128 + lane;
    const int cb  = ca + 64;
    const int sza = ((ca & 3) ^ ((ca >> 3) & 3)) * 8;
    const int szb = ((cb & 3) ^ ((cb >> 3) & 3)) * 8;
    const size_t arow0 = (size_t)(r0 + (ca >> 2)) * Kp + sza;
    const size_t brow0 = (size_t)(c0 + (ca >> 2)) * Kp + sza;
    const size_t arow1 = (size_t)(r0 + (cb >> 2)) * Kp + szb;
    const size_t brow1 = (size_t)(c0 + (cb >> 2)) * Kp + szb;

    f32x4 acc[4][4];
#pragma unroll
    for (int i = 0; i < 4; ++i)
#pragma unroll
        for (int j = 0; j < 4; ++j) acc[i][j] = (f32x4){0.f, 0.f, 0.f, 0.f};

    const int kt0 = blockIdx.z * ktn;
    auto stage = [&](int kt, int buf) {
        int k0 = kt * 32;
        gload16(A + arow0 + k0, &sA[buf][ca * 8]);
        gload16(B + brow0 + k0, &sB[buf][ca * 8]);
        gload16(A + arow1 + k0, &sA[buf][cb * 8]);
        gload16(B + brow1 + k0, &sB[buf][cb * 8]);
    };
    auto compute = [&](int buf) {
        bf16x8 af[4], bfr[4];
#pragma unroll
        for (int f = 0; f < 4; ++f) {
            af[f]  = *reinterpret_cast<const bf16x8*>(&sA[buf][(wr + f * 16 + l15) * 32 + kk + pco]);
            bfr[f] = *reinterpret_cast<const bf16x8*>(&sB[buf][(wc + f * 16 + l15) * 32 + kk + pco]);
        }
#pragma unroll
        for (int fr = 0; fr < 4; ++fr)
#pragma unroll
            for (int fc = 0; fc < 4; ++fc)
                acc[fr][fc] = __builtin_amdgcn_mfma_f32_16x16x32_bf16(af[fr], bfr[fc], acc[fr][fc], 0, 0, 0);
    };

    const int NT = ktn;
    stage(kt0, 0);
    if (NT > 1) stage(kt0 + 1, 1);
    int bcur = 0;
    for (int t = 0; t < NT - 1; ++t) {
        asm volatile("s_waitcnt vmcnt(4)" ::: "memory");
        __builtin_amdgcn_s_barrier();
        __builtin_amdgcn_sched_barrier(0);
        if (t + 2 < NT) {
            int bn = bcur + 2; if (bn >= 3) bn -= 3;
            stage(kt0 + t + 2, bn);
        }
        __builtin_amdgcn_sched_barrier(0);
        compute(bcur);
        bcur = (bcur == 2) ? 0 : bcur + 1;
    }
    asm volatile("s_waitcnt vmcnt(0)" ::: "memory");
    __builtin_amdgcn_s_barrier();
    __builtin_amdgcn_sched_barrier(0);
    compute(bcur);

    const int rowb = r0 + wr + (lane >> 4) * 4;
    const int colb = c0 + wc + l15;
    if (EPI == EPI_PART) {
        float* pp = (float*)outp + (size_t)blockIdx.z * zstride;
#pragma unroll
        for (int fc = 0; fc < 4; ++fc) {
            int col = colb + fc * 16;
#pragma unroll
            for (int fr = 0; fr < 4; ++fr)
#pragma unroll
                for (int r2 = 0; r2 < 4; ++r2)
                    pp[(size_t)(rowb + fr * 16 + r2) * ldc + col] = acc[fr][fc][r2];
        }
        return;
    }
#pragma unroll
    for (int fc = 0; fc < 4; ++fc) {
        int col = colb + fc * 16;
        float bv = (EPI != EPI_NONE) ? bias[col] : 0.f;
#pragma unroll
        for (int fr = 0; fr < 4; ++fr) {
#pragma unroll
            for (int r2 = 0; r2 < 4; ++r2) {
                int row = rowb + fr * 16 + r2;
                if (row >= Rlim) continue;
                float v = acc[fr][fc][r2] + bv;
                if (EPI == EPI_BIAS_RESID) v += resid[(size_t)row * ldc + col];
                if (EPI == EPI_BIAS_GELU)  v = 0.5f * v * (1.f + erff(v * 0.70710678118f));
                if (OF32) ((float*)outp)[(size_t)row * ldc + col] = v;
                else      ((u16*)outp)[(size_t)row * ldc + col] = f2bf(v);
            }
        }
    }
}

// 64x128-tile GEMM: 4 blocks/CU. Staging: 2 B chunks + 1 A chunk per thread.
template <int EPI, bool OF32>
__global__ __launch_bounds__(256, 4)
void gemm64_kernel(const u16* __restrict__ A, const u16* __restrict__ B,
                   const float* __restrict__ bias, const float* __restrict__ resid,
                   void* __restrict__ outp, int Kp, int ldc, int Rlim)
{
    __shared__ u16 sA[3][2048];
    __shared__ u16 sB[3][4096];
    const int tid  = threadIdx.x;
    const int lane = tid & 63;
    const int w    = tid >> 6;

    const unsigned gy  = gridDim.y;
    const unsigned nwg = gridDim.x * gy;
    const unsigned lin = blockIdx.x + blockIdx.y * gridDim.x;
    const unsigned id2 = xcd_map(lin, nwg);
    const int c0 = (int)(id2 / gy) * 128;
    const int r0 = (int)(id2 - (id2 / gy) * gy) * 64;

    const int wr  = (w >> 1) * 32;
    const int wc  = (w & 1) * 64;
    const int l15 = lane & 15;
    const int kk  = (lane >> 4) * 8;
    const int pco = (((lane >> 4) ^ ((l15 >> 1) & 3)) * 8) - kk;

    const int cB0 = tid, cB1 = tid + 256, cA = tid;
    const size_t bsrc0 = (size_t)(c0 + (cB0 >> 2)) * Kp + ((cB0 & 3) ^ ((cB0 >> 3) & 3)) * 8;
    const size_t bsrc1 = (size_t)(c0 + (cB1 >> 2)) * Kp + ((cB1 & 3) ^ ((cB1 >> 3) & 3)) * 8;
    const size_t asrc  = (size_t)(r0 + (cA  >> 2)) * Kp + ((cA  & 3) ^ ((cA  >> 3) & 3)) * 8;

    f32x4 acc[2][4];
#pragma unroll
    for (int i = 0; i < 2; ++i)
#pragma unroll
        for (int j = 0; j < 4; ++j) acc[i][j] = (f32x4){0.f, 0.f, 0.f, 0.f};

    auto stage = [&](int kt, int buf) {
        int k0 = kt * 32;
        gload16(B + bsrc0 + k0, &sB[buf][cB0 * 8]);
        gload16(B + bsrc1 + k0, &sB[buf][cB1 * 8]);
        gload16(A + asrc  + k0, &sA[buf][cA * 8]);
    };
    auto compute = [&](int buf) {
        bf16x8 af[2], bfr[4];
#pragma unroll
        for (int f = 0; f < 2; ++f)
            af[f]  = *reinterpret_cast<const bf16x8*>(&sA[buf][(wr + f * 16 + l15) * 32 + kk + pco]);
#pragma unroll
        for (int f = 0; f < 4; ++f)
            bfr[f] = *reinterpret_cast<const bf16x8*>(&sB[buf][(wc + f * 16 + l15) * 32 + kk + pco]);
#pragma unroll
        for (int fr = 0; fr < 2; ++fr)
#pragma unroll
            for (int fc = 0; fc < 4; ++fc)
                acc[fr][fc] = __builtin_amdgcn_mfma_f32_16x16x32_bf16(af[fr], bfr[fc], acc[fr][fc], 0, 0, 0);
    };

    const int NT = Kp >> 5;
    stage(0, 0);
    stage(1, 1);
    int bcur = 0;
    for (int t = 0; t < NT - 1; ++t) {
        asm volatile("s_waitcnt vmcnt(3)" ::: "memory");
        __builtin_amdgcn_s_barrier();
        __builtin_amdgcn_sched_barrier(0);
        if (t + 2 < NT) {
            int bn = bcur + 2; if (bn >= 3) bn -= 3;
            stage(t + 2, bn);
        }
        __builtin_amdgcn_sched_barrier(0);
        compute(bcur);
        bcur = (bcur == 2) ? 0 : bcur + 1;
    }
    asm volatile("s_waitcnt vmcnt(0)" ::: "memory");
    __builtin_amdgcn_s_barrier();
    __builtin_amdgcn_sched_barrier(0);
    compute(bcur);

    const int rowb = r0 + wr + (lane >> 4) * 4;
    const int colb = c0 + wc + l15;
#pragma unroll
    for (int fc = 0; fc < 4; ++fc) {
        int col = colb + fc * 16;
        float bv = (EPI != EPI_NONE) ? bias[col] : 0.f;
#pragma unroll
        for (int fr = 0; fr < 2; ++fr) {
#pragma unroll
            for (int r2 = 0; r2 < 4; ++r2) {
                int row = rowb + fr * 16 + r2;
                if (row >= Rlim) continue;
                float v = acc[fr][fc][r2] + bv;
                if (EPI == EPI_BIAS_RESID) v += resid[(size_t)row * ldc + col];
                if (EPI == EPI_BIAS_GELU)  v = 0.5f * v * (1.f + erff(v * 0.70710678118f));
                if (OF32) ((float*)outp)[(size_t)row * ldc + col] = v;
                else      ((u16*)outp)[(size_t)row * ldc + col] = f2bf(v);
            }
        }
    }
}

// 32x128-tile GEMM for small-B residency-bound shapes (patch, proj, down).
template <int EPI, bool OF32>
__global__ __launch_bounds__(256, 4)
void gemm32_kernel(const u16* __restrict__ A, const u16* __restrict__ B,
                   const float* __restrict__ bias, const float* __restrict__ resid,
                   void* __restrict__ outp, int Kp, int ldc, int Rlim)
{
    __shared__ u16 sA[3][1024];
    __shared__ u16 sB[3][4096];
    const int tid  = threadIdx.x;
    const int lane = tid & 63;
    const int w    = tid >> 6;

    const unsigned gy  = gridDim.y;
    const unsigned nwg = gridDim.x * gy;
    const unsigned lin = blockIdx.x + blockIdx.y * gridDim.x;
    const unsigned id2 = xcd_map(lin, nwg);
    const int c0 = (int)(id2 / gy) * 128;
    const int r0 = (int)(id2 - (id2 / gy) * gy) * 32;

    const int wc  = w * 32;
    const int l15 = lane & 15;
    const int kk  = (lane >> 4) * 8;
    const int pco = (((lane >> 4) ^ ((l15 >> 1) & 3)) * 8) - kk;

    const int cB0 = tid, cB1 = tid + 256, cA = tid & 127;
    const size_t bsrc0 = (size_t)(c0 + (cB0 >> 2)) * Kp + ((cB0 & 3) ^ ((cB0 >> 3) & 3)) * 8;
    const size_t bsrc1 = (size_t)(c0 + (cB1 >> 2)) * Kp + ((cB1 & 3) ^ ((cB1 >> 3) & 3)) * 8;
    const size_t asrc  = (size_t)(r0 + (cA  >> 2)) * Kp + ((cA  & 3) ^ ((cA  >> 3) & 3)) * 8;

    f32x4 acc[2][2];
#pragma unroll
    for (int i = 0; i < 2; ++i)
#pragma unroll
        for (int j = 0; j < 2; ++j) acc[i][j] = (f32x4){0.f, 0.f, 0.f, 0.f};

    auto stage = [&](int kt, int buf) {
        int k0 = kt * 32;
        gload16(B + bsrc0 + k0, &sB[buf][cB0 * 8]);
        gload16(B + bsrc1 + k0, &sB[buf][cB1 * 8]);
        gload16(A + asrc  + k0, &sA[buf][cA * 8]);
    };
    auto compute = [&](int buf) {
        bf16x8 af[2], bfr[2];
#pragma unroll
        for (int f = 0; f < 2; ++f) {
            af[f]  = *reinterpret_cast<const bf16x8*>(&sA[buf][(f * 16 + l15) * 32 + kk + pco]);
            bfr[f] = *reinterpret_cast<const bf16x8*>(&sB[buf][(wc + f * 16 + l15) * 32 + kk + pco]);
        }
#pragma unroll
        for (int fr = 0; fr < 2; ++fr)
#pragma unroll
            for (int fc = 0; fc < 2; ++fc)
                acc[fr][fc] = __builtin_amdgcn_mfma_f32_16x16x32_bf16(af[fr], bfr[fc], acc[fr][fc], 0, 0, 0);
    };

    const int NT = Kp >> 5;
    stage(0, 0);
    stage(1, 1);
    int bcur = 0;
    for (int t = 0; t < NT - 1; ++t) {
        asm volatile("s_waitcnt vmcnt(3)" ::: "memory");
        __builtin_amdgcn_s_barrier();
        __builtin_amdgcn_sched_barrier(0);
        if (t + 2 < NT) {
            int bn = bcur + 2; if (bn >= 3) bn -= 3;
            stage(t + 2, bn);
        }
        __builtin_amdgcn_sched_barrier(0);
        compute(bcur);
        bcur = (bcur == 2) ? 0 : bcur + 1;
    }
    asm volatile("s_waitcnt vmcnt(0)" ::: "memory");
    __builtin_amdgcn_s_barrier();
    __builtin_amdgcn_sched_barrier(0);
    compute(bcur);

    const int rowb = r0 + (lane >> 4) * 4;
    const int colb = c0 + wc + l15;
#pragma unroll
    for (int fc = 0; fc < 2; ++fc) {
        int col = colb + fc * 16;
        float bv = (EPI != EPI_NONE) ? bias[col] : 0.f;
#pragma unroll
        for (int fr = 0; fr < 2; ++fr) {
#pragma unroll
            for (int r2 = 0; r2 < 4; ++r2) {
                int row = rowb + fr * 16 + r2;
                if (row >= Rlim) continue;
                float v = acc[fr][fc][r2] + bv;
                if (EPI == EPI_BIAS_RESID) v += resid[(size_t)row * ldc + col];
                if (EPI == EPI_BIAS_GELU)  v = 0.5f * v * (1.f + erff(v * 0.70710678118f));
                if (OF32) ((float*)outp)[(size_t)row * ldc + col] = v;
                else      ((u16*)outp)[(size_t)row * ldc + col] = f2bf(v);
            }
        }
    }
}

// Split-K reduce: out = [gelu](sum_s part[s] + bias). total4 = R*C/4.
template <int GELU, bool OF32>
__global__ void reduce_kernel(const float* __restrict__ part, const float* __restrict__ bias,
                              void* __restrict__ outp, int C, int S, size_t zstride, int total4)
{
    int i = blockIdx.x * 256 + threadIdx.x;
    if (i >= total4) return;
    int cq = C >> 2;
    int rr = i / cq;
    int cc = (i - rr * cq) * 4;
    size_t bidx = (size_t)rr * C + cc;
    float4 s = *reinterpret_cast<const float4*>(&part[bidx]);
    for (int z = 1; z < S; ++z) {
        float4 p = *reinterpret_cast<const float4*>(&part[z * zstride + bidx]);
        s.x += p.x; s.y += p.y; s.z += p.z; s.w += p.w;
    }
    float4 b = *reinterpret_cast<const float4*>(&bias[cc]);
    s.x += b.x; s.y += b.y; s.z += b.z; s.w += b.w;
    if (GELU) {
        s.x = 0.5f * s.x * (1.f + erff(s.x * 0.70710678118f));
        s.y = 0.5f * s.y * (1.f + erff(s.y * 0.70710678118f));
        s.z = 0.5f * s.z * (1.f + erff(s.z * 0.70710678118f));
        s.w = 0.5f * s.w * (1.f + erff(s.w * 0.70710678118f));
    }
    if (OF32) {
        *reinterpret_cast<float4*>(&((float*)outp)[bidx]) = s;
    } else {
        u16 v[4] = { f2bf(s.x), f2bf(s.y), f2bf(s.z), f2bf(s.w) };
        *reinterpret_cast<uint2*>(&((u16*)outp)[bidx]) = *reinterpret_cast<const uint2*>(v);
    }
}

__global__ void rms_kernel(const float* __restrict__ x, const float* __restrict__ w,
                           u16* __restrict__ out, int cols)
{
    const int row = blockIdx.x;
    const int tid = threadIdx.x;
    const float* xr = x + (size_t)row * cols;
    float ss = 0.f;
    for (int c = tid; c < cols; c += 256) { float v = xr[c]; ss += v * v; }
#pragma unroll
    for (int m = 1; m < 64; m <<= 1) ss += __shfl_xor(ss, m);
    __shared__ float wsum[4];
    if ((tid & 63) == 0) wsum[tid >> 6] = ss;
    __syncthreads();
    float tot = wsum[0] + wsum[1] + wsum[2] + wsum[3];
    float rs = rsqrtf(tot / (float)cols + 1e-6f);
    u16* orow = out + (size_t)row * cols;
    for (int c = tid; c < cols; c += 256) orow[c] = f2bf(xr[c] * rs * w[c]);
}

// In-place RoPE on bf16 q,k halves of qkv.
__global__ void rope_kernel(u16* __restrict__ qkv, const float* __restrict__ cosb,
                            const float* __restrict__ sinb)
{
    int idx = blockIdx.x * 256 + threadIdx.x;   // < 1,024,000
    int n   = idx / 640;
    int rem = idx - n * 640;
    int hh  = rem / 40;
    int d   = rem - hh * 40;
    float c0 = cosb[n * 80 + d];
    float s0 = sinb[n * 80 + d];
    float c1 = cosb[n * 80 + d + 40];
    float s1 = sinb[n * 80 + d + 40];
    size_t base = (size_t)n * 3840 + hh * 80;
    float a = bf2f(qkv[base + d]), b = bf2f(qkv[base + d + 40]);
    qkv[base + d]      = f2bf(a * c0 - b * s0);
    qkv[base + d + 40] = f2bf(b * c1 + a * s1);
    base += 1280;
    a = bf2f(qkv[base + d]); b = bf2f(qkv[base + d + 40]);
    qkv[base + d]      = f2bf(a * c0 - b * s0);
    qkv[base + d + 40] = f2bf(b * c1 + a * s1);
}

// silu(gate)*up from fused [1664][6912] buffer -> packed [1664][3456].
__global__ void silu_mul_kernel(const u16* __restrict__ gu, u16* __restrict__ outb)
{
    int idx = blockIdx.x * 256 + threadIdx.x;
    if (idx >= 1664 * 432) return;
    int row = idx / 432, c8 = (idx - row * 432) * 8;
    u16 gv[8], uv[8];
    *reinterpret_cast<uint4*>(gv) = *reinterpret_cast<const uint4*>(&gu[(size_t)row * 6912 + c8]);
    *reinterpret_cast<uint4*>(uv) = *reinterpret_cast<const uint4*>(&gu[(size_t)row * 6912 + 3456 + c8]);
#pragma unroll
    for (int j = 0; j < 8; ++j) {
        float x = bf2f(gv[j]);
        gv[j] = f2bf(x / (1.f + __expf(-x)) * bf2f(uv[j]));
    }
    *reinterpret_cast<uint4*>(&outb[(size_t)row * 3456 + c8]) = *reinterpret_cast<const uint4*>(gv);
}

// Flash attention (r7-proven): 256 threads, QBLK=64, double-buffered K/V LDS,
// reg-staged loads, conflict-free packed-u32 V transpose, 1 barrier/tile.
__global__ __launch_bounds__(256, 2)
void attn_kernel(const u16* __restrict__ qkv, u16* __restrict__ o)
{
    __shared__ __align__(16) u16      Klds[2][64][104];
    __shared__ __align__(16) unsigned Vt32[2][80][36];
    __shared__ __align__(16) u16      Plds[4][16][72];
    const int tid  = threadIdx.x;
    const int lane = tid & 63;
    const int w    = tid >> 6;
    const int l15  = lane & 15;
    const int kk   = (lane >> 4) * 8;
    unsigned lin = blockIdx.y * 25 + blockIdx.x;
    unsigned id2 = (lin & 7) * 50 + (lin >> 3);
    const int hh = (int)(id2 / 25);
    const int qt = (int)(id2 - hh * 25);
    const float scale = 0.11180339887498949f;

    const int koff = 1280 + hh * 80;
    const int voff = 2560 + hh * 80;

    {
        int r  = tid >> 2;
        int cq = 80 + (tid & 3) * 4;
        *reinterpret_cast<uint2*>(&Klds[0][r][cq]) = make_uint2(0u, 0u);
        *reinterpret_cast<uint2*>(&Klds[1][r][cq]) = make_uint2(0u, 0u);
    }

    const int qrow = qt * 64 + w * 16 + l15;
    bf16x8 aq[3];
#pragma unroll
    for (int s = 0; s < 3; ++s) {
        int d = 32 * s + kk;
        union { bf16x8 v; uint4 q; } uu;
        if (d < 80) uu.q = *reinterpret_cast<const uint4*>(&qkv[(size_t)qrow * 3840 + hh * 80 + d]);
        else        uu.q = make_uint4(0u, 0u, 0u, 0u);
        aq[s] = uu.v;
    }

    const int kc0 = tid, kc1 = tid + 256, kc2 = tid + 512;
    const int kr0 = kc0 / 10, k80 = (kc0 - kr0 * 10) * 8;
    const int kr1 = kc1 / 10, k81 = (kc1 - kr1 * 10) * 8;
    const int kr2 = kc2 / 10, k82 = (kc2 - kr2 * 10) * 8;
    const size_t ksrc0 = (size_t)kr0 * 3840 + koff + k80;
    const size_t ksrc1 = (size_t)kr1 * 3840 + koff + k81;
    const size_t ksrc2 = (size_t)kr2 * 3840 + koff + k82;
    const int rpA = tid & 31, gA = tid >> 5;
    const int gB = 8 + (tid >> 5);
    const size_t vsrcA = (size_t)(2 * rpA) * 3840 + voff + gA * 8;
    const size_t vsrcB = (size_t)(2 * rpA) * 3840 + voff + gB * 8;

    uint4 kg0, kg1, kg2, va0, va1, vb0, vb1;
    auto LOADR = [&](int kb) {
        size_t tb = (size_t)kb * 245760;
        kg0 = *reinterpret_cast<const uint4*>(&qkv[tb + ksrc0]);
        kg1 = *reinterpret_cast<const uint4*>(&qkv[tb + ksrc1]);
        if (tid < 128) kg2 = *reinterpret_cast<const uint4*>(&qkv[tb + ksrc2]);
        va0 = *reinterpret_cast<const uint4*>(&qkv[tb + vsrcA]);
        va1 = *reinterpret_cast<const uint4*>(&qkv[tb + vsrcA + 3840]);
        if (tid < 64) {
            vb0 = *reinterpret_cast<const uint4*>(&qkv[tb + vsrcB]);
            vb1 = *reinterpret_cast<const uint4*>(&qkv[tb + vsrcB + 3840]);
        }
    };
    auto STORE = [&](int b) {
        *reinterpret_cast<uint4*>(&Klds[b][kr0][k80]) = kg0;
        *reinterpret_cast<uint4*>(&Klds[b][kr1][k81]) = kg1;
        if (tid < 128) *reinterpret_cast<uint4*>(&Klds[b][kr2][k82]) = kg2;
        union { uint4 q; u16 h[8]; } xa0, xa1;
        xa0.q = va0; xa1.q = va1;
#pragma unroll
        for (int j = 0; j < 8; ++j)
            Vt32[b][gA * 8 + j][rpA] = (unsigned)xa0.h[j] | ((unsigned)xa1.h[j] << 16);
        if (tid < 64) {
            union { uint4 q; u16 h[8]; } xb0, xb1;
            xb0.q = vb0; xb1.q = vb1;
#pragma unroll
            for (int j = 0; j < 8; ++j)
                Vt32[b][gB * 8 + j][rpA] = (unsigned)xb0.h[j] | ((unsigned)xb1.h[j] << 16);
        }
    };

    f32x4 acc_o[5];
#pragma unroll
    for (int fd = 0; fd < 5; ++fd) acc_o[fd] = (f32x4){0.f, 0.f, 0.f, 0.f};
    float m[4], lsum[4];
#pragma unroll
    for (int r2 = 0; r2 < 4; ++r2) { m[r2] = -__builtin_inff(); lsum[r2] = 0.f; }

    LOADR(0);
    STORE(0);
    __syncthreads();
    int cur = 0;

    for (int kb = 0; kb < 25; ++kb) {
        if (kb < 24) LOADR(kb + 1);

        f32x4 sf[4];
#pragma unroll
        for (int fc = 0; fc < 4; ++fc) {
            f32x4 c = (f32x4){0.f, 0.f, 0.f, 0.f};
#pragma unroll
            for (int s = 0; s < 3; ++s)
                c = __builtin_amdgcn_mfma_f32_16x16x32_bf16(
                        aq[s],
                        *reinterpret_cast<const bf16x8*>(&Klds[cur][fc * 16 + l15][32 * s + kk]),
                        c, 0, 0, 0);
            sf[fc] = c * scale;
        }

        float mx[4];
#pragma unroll
        for (int r2 = 0; r2 < 4; ++r2)
            mx[r2] = fmaxf(fmaxf(sf[0][r2], sf[1][r2]), fmaxf(sf[2][r2], sf[3][r2]));
#pragma unroll
        for (int msk = 1; msk <= 8; msk <<= 1)
#pragma unroll
            for (int r2 = 0; r2 < 4; ++r2)
                mx[r2] = fmaxf(mx[r2], __shfl_xor(mx[r2], msk));
        float alpha[4];
#pragma unroll
        for (int r2 = 0; r2 < 4; ++r2) {
            float mn = fmaxf(m[r2], mx[r2]);
            alpha[r2] = __expf(m[r2] - mn);
            m[r2] = mn;
        }
        float psum[4] = {0.f, 0.f, 0.f, 0.f};
#pragma unroll
        for (int fc = 0; fc < 4; ++fc)
#pragma unroll
            for (int r2 = 0; r2 < 4; ++r2) {
                float p = __expf(sf[fc][r2] - m[r2]);
                sf[fc][r2] = p;
                psum[r2] += p;
            }
#pragma unroll
        for (int msk = 1; msk <= 8; msk <<= 1)
#pragma unroll
            for (int r2 = 0; r2 < 4; ++r2) psum[r2] += __shfl_xor(psum[r2], msk);
#pragma unroll
        for (int r2 = 0; r2 < 4; ++r2) lsum[r2] = lsum[r2] * alpha[r2] + psum[r2];
#pragma unroll
        for (int fd = 0; fd < 5; ++fd)
#pragma unroll
            for (int r2 = 0; r2 < 4; ++r2) acc_o[fd][r2] *= alpha[r2];

        const int prow = (lane >> 4) * 4;
#pragma unroll
        for (int fc = 0; fc < 4; ++fc)
#pragma unroll
            for (int r2 = 0; r2 < 4; ++r2)
                Plds[w][prow + r2][fc * 16 + l15] = f2bf(sf[fc][r2]);

        bf16x8 ap[2];
#pragma unroll
        for (int ks = 0; ks < 2; ++ks)
            ap[ks] = *reinterpret_cast<const bf16x8*>(&Plds[w][l15][32 * ks + kk]);
#pragma unroll
        for (int fd = 0; fd < 5; ++fd) {
            const u16* vrow = reinterpret_cast<const u16*>(&Vt32[cur][fd * 16 + l15][0]);
#pragma unroll
            for (int ks = 0; ks < 2; ++ks)
                acc_o[fd] = __builtin_amdgcn_mfma_f32_16x16x32_bf16(
                        ap[ks],
                        *reinterpret_cast<const bf16x8*>(&vrow[32 * ks + kk]),
                        acc_o[fd], 0, 0, 0);
        }

        if (kb < 24) STORE(cur ^ 1);
        __syncthreads();
        cur ^= 1;
    }

    float inv[4];
#pragma unroll
    for (int r2 = 0; r2 < 4; ++r2) inv[r2] = 1.f / lsum[r2];
    const int orow = qt * 64 + w * 16 + (lane >> 4) * 4;
    const int ocol = hh * 80 + l15;
#pragma unroll
    for (int fd = 0; fd < 5; ++fd)
#pragma unroll
        for (int r2 = 0; r2 < 4; ++r2)
            o[(size_t)(orow + r2) * 1280 + ocol + fd * 16] = f2bf(acc_o[fd][r2] * inv[r2]);
}

extern "C" void kernel_launch(void* const* d_in, const int* in_sizes, int n_in,
                              void* d_out, int out_size, void* d_ws, size_t ws_size,
                              hipStream_t stream)
{
    const float* pixel  = (const float*)d_in[0];
    const float* cosb   = (const float*)d_in[1];
    const float* sinb   = (const float*)d_in[2];
    const float* patchw = (const float*)d_in[3];
    const float* n1w    = (const float*)d_in[4];
    const float* qkvw   = (const float*)d_in[5];
    const float* qkvb   = (const float*)d_in[6];
    const float* projw  = (const float*)d_in[7];
    const float* projb  = (const float*)d_in[8];
    const float* n2w    = (const float*)d_in[9];
    const float* gatew  = (const float*)d_in[10];
    const float* gateb  = (const float*)d_in[11];
    const float* upw    = (const float*)d_in[12];
    const float* upb    = (const float*)d_in[13];
    const float* downw  = (const float*)d_in[14];
    const float* downb  = (const float*)d_in[15];
    const float* lnqw   = (const float*)d_in[16];
    const float* m1w    = (const float*)d_in[17];
    const float* m1b    = (const float*)d_in[18];
    const float* m2w    = (const float*)d_in[19];
    const float* m2b    = (const float*)d_in[20];
    float* out = (float*)d_out;

    char* base = (char*)d_ws;
    float* x      = (float*)(base);                       //  1664x1280 f32
    u16*   h      = (u16*)(base + 8519680);               //  1664x1280
    u16*   qbuf   = (u16*)(base + 12779520);              //  1664x3840
    u16*   pix16  = qbuf;                                 //  alias (pre-loop, 1664x1216)
    u16*   gsep   = (u16*)(base + 25559040);              //  1664x3456
    u16*   o      = gsep;                                 //  alias (attn->proj)
    u16*   pw16   = gsep;                                 //  alias (pre-loop, 1280x1216)
    u16*   gu     = (u16*)(base + 37060608);              //  1664x6912
    u16*   t1     = gu;                                   //  alias (post-loop, 512x5120)
    float* guB    = (float*)(base + 60063744);            //  4x6912 f32
    u16*   qkvw16 = (u16*)(base + 60174336);              //  4x3840x1280
    u16*   projw16= (u16*)(base + 99495936);              //  4x1280x1280
    u16*   guw16  = (u16*)(base + 112603136);             //  4x6912x1280
    u16*   downw16= (u16*)(base + 183382016);             //  4x1280x3456 (end 218.8MB)
    u16*   m1w16  = guw16;                                //  alias (post-loop)
    u16*   m2w16  = (u16*)(base + 112603136 + 52428800);  //  alias (post-loop)
    float* part   = (float*)qkvw16;                       //  alias (post-loop, 52.4MB)

    dim3 blk(256);

    cvtall_kernel<<<10118, blk, 0, stream>>>(pixel, patchw, qkvw, projw, gatew, upw, downw,
                                             pix16, pw16, qkvw16, projw16, guw16, downw16);
    gub_kernel<<<108, blk, 0, stream>>>(gateb, upb, guB);

    gemm32_kernel<EPI_NONE, true><<<dim3(10,52), blk, 0, stream>>>(pix16, pw16, nullptr, nullptr, x, 1216, 1280, 1664);
    for (int i = 0; i < 4; ++i) {
        rms_kernel<<<1600, blk, 0, stream>>>(x, n1w + i*1280, h, 1280);
        gemm64_kernel<EPI_BIAS, false><<<dim3(30,26), blk, 0, stream>>>(h, qkvw16 + (size_t)i*4915200, qkvb + i*3840, nullptr, qbuf, 1280, 3840, 1664);
        rope_kernel<<<4000, blk, 0, stream>>>(qbuf, cosb, sinb);
        attn_kernel<<<dim3(25,16), blk, 0, stream>>>(qbuf, o);
        gemm32_kernel<EPI_BIAS_RESID, true><<<dim3(10,52), blk, 0, stream>>>(o, projw16 + (size_t)i*1638400, projb + i*1280, x, x, 1280, 1280, 1664);
        rms_kernel<<<1600, blk, 0, stream>>>(x, n2w + i*1280, h, 1280);
        gemm16_kernel<EPI_BIAS, false><<<dim3(54,13), blk, 0, stream>>>(h, guw16 + (size_t)i*8847360, guB + i*6912, nullptr, gu, 1280, 6912, 1664, 40, 0);
        silu_mul_kernel<<<2808, blk, 0, stream>>>(gu, gsep);
        gemm32_kernel<EPI_BIAS_RESID, true><<<dim3(10,52), blk, 0, stream>>>(gsep, downw16 + (size_t)i*4423680, downb + i*1280, x, x, 3456, 1280, 1664);
    }
    cvtmm_kernel<<<5440, blk, 0, stream>>>(m1w, m2w, m1w16, m2w16);
    rms_kernel<<<1600, blk, 0, stream>>>(x, lnqw, h, 1280);
    gemm16_kernel<EPI_PART, false><<<dim3(40,4,5), blk, 0, stream>>>(h, m1w16, nullptr, nullptr, part, 5120, 5120, 512, 32, 2621440);
    reduce_kernel<1, false><<<2560, blk, 0, stream>>>(part, m1b, t1, 5120, 5, 2621440, 655360);
    gemm16_kernel<EPI_PART, false><<<dim3(28,4,5), blk, 0, stream>>>(t1, m2w16, nullptr, nullptr, part, 5120, 3584, 512, 32, 1835008);
    reduce_kernel<0, true><<<1400, blk, 0, stream>>>(part, m2b, out, 3584, 5, 1835008, 358400);
}